// Round 1
// baseline (473.695 us; speedup 1.0000x reference)
//
#include <hip/hip_runtime.h>

// Walsh-Hadamard (n=4096) per row + affine epilogue: out = scale * (H x)/64 + shift
// One 256-thread block per row. 4096 = 16 (regs) x 16 x 16 via two LDS transposes.
// LDS row stride 17 words: pad gives >=2-way-only bank patterns in every phase.

#define ROW 4096
#define STR 17  // padded LDS row stride (words)

__device__ __forceinline__ void wht16(float v[16]) {
#pragma unroll
  for (int h = 1; h < 16; h <<= 1) {
#pragma unroll
    for (int i = 0; i < 16; ++i) {
      if ((i & h) == 0) {
        float a = v[i], b = v[i | h];
        v[i] = a + b;
        v[i | h] = a - b;
      }
    }
  }
}

__global__ __launch_bounds__(256) void AdaptiveHadamardTransform_kernel(
    const float* __restrict__ x, const float* __restrict__ scale,
    const float* __restrict__ shift, float* __restrict__ out) {
  __shared__ float lds[256 * STR];  // 17408 B

  const int t = threadIdx.x;
  const long long base = (long long)blockIdx.x * ROW;
  const float* xr = x + base;

  float v[16];

  // ---- Round 1: thread t holds elements e = r*256 + t (vary high digit i2).
  // Each scalar load: 64 lanes read 256 consecutive bytes -> fully coalesced.
#pragma unroll
  for (int r = 0; r < 16; ++r) v[r] = xr[r * 256 + t];
  wht16(v);

  // logical index (i2, i1, i0) stored at lds[(i2*16 + i1)*STR + i0]
  {
    const int i1 = t >> 4, i0 = t & 15;
#pragma unroll
    for (int r = 0; r < 16; ++r) lds[(r * 16 + i1) * STR + i0] = v[r];
  }
  __syncthreads();

  // ---- Round 2: thread t holds (i0 = t&15, i2 = t>>4), vary middle digit i1.
  {
    const int i2 = t >> 4, i0 = t & 15;
#pragma unroll
    for (int r = 0; r < 16; ++r) v[r] = lds[(i2 * 16 + r) * STR + i0];
    wht16(v);
    // write back to the SAME addresses this thread read -> no barrier needed first
#pragma unroll
    for (int r = 0; r < 16; ++r) lds[(i2 * 16 + r) * STR + i0] = v[r];
  }
  __syncthreads();

  // ---- Round 3: thread t owns row u = t (i2 = t>>4, i1 = t&15), vary i0.
  // addr = t*17 + r : 17 odd -> 2-way max bank aliasing (free).
#pragma unroll
  for (int r = 0; r < 16; ++r) v[r] = lds[t * STR + r];
  wht16(v);

  // ---- Epilogue: e = 16*t + r ; normalize 1/sqrt(4096) = 1/64 exactly.
  const float norm = 0.015625f;
  const float4* sc4 = reinterpret_cast<const float4*>(scale + 16 * t);
  const float4* sh4 = reinterpret_cast<const float4*>(shift + 16 * t);
  float4* o4 = reinterpret_cast<float4*>(out + base + 16 * t);
#pragma unroll
  for (int j = 0; j < 4; ++j) {
    const float4 s = sc4[j];
    const float4 h = sh4[j];
    float4 o;
    o.x = fmaf(s.x, v[4 * j + 0] * norm, h.x);
    o.y = fmaf(s.y, v[4 * j + 1] * norm, h.y);
    o.z = fmaf(s.z, v[4 * j + 2] * norm, h.z);
    o.w = fmaf(s.w, v[4 * j + 3] * norm, h.w);
    o4[j] = o;
  }
}

extern "C" void kernel_launch(void* const* d_in, const int* in_sizes, int n_in,
                              void* d_out, int out_size, void* d_ws, size_t ws_size,
                              hipStream_t stream) {
  const float* x = (const float*)d_in[0];
  const float* scale = (const float*)d_in[1];
  const float* shift = (const float*)d_in[2];
  float* out = (float*)d_out;

  const int rows = in_sizes[0] / ROW;  // 4*4096 = 16384
  AdaptiveHadamardTransform_kernel<<<rows, 256, 0, stream>>>(x, scale, shift, out);
}

// Round 2
// 441.613 us; speedup vs baseline: 1.0726x; 1.0726x over previous
//
#include <hip/hip_runtime.h>

// Walsh-Hadamard (n=4096) per row + affine epilogue: out = scale * (H x)/64 + shift
// One 256-thread block per row. 4096 = 16 x 16 x 16 (H16 (x) H16 (x) H16).
// Digit order chosen so the GLOBAL LOAD side is float4-vectorized (16 B/lane):
//   R1: regs, transform i0 (thread t owns 16 contiguous elements -> 4x float4 loads)
//   R2: LDS,  transform i1 (pad-17 rows: 2-way bank aliasing = free)
//   R3: LDS,  transform i2 -> final ownership e = r*256 + t -> coalesced 256B/instr
//             nontemporal dword stores (keep L3 warm for the input stream).

#define ROW 4096
#define STR 17  // padded LDS row stride (words)

__device__ __forceinline__ void wht16(float v[16]) {
#pragma unroll
  for (int h = 1; h < 16; h <<= 1) {
#pragma unroll
    for (int i = 0; i < 16; ++i) {
      if ((i & h) == 0) {
        float a = v[i], b = v[i | h];
        v[i] = a + b;
        v[i | h] = a - b;
      }
    }
  }
}

__global__ __launch_bounds__(256) void AdaptiveHadamardTransform_kernel(
    const float* __restrict__ x, const float* __restrict__ scale,
    const float* __restrict__ shift, float* __restrict__ out) {
  __shared__ float lds[256 * STR];  // 17408 B

  const int t = threadIdx.x;
  const long long base = (long long)blockIdx.x * ROW;

  float v[16];

  // ---- R1: thread t loads elements e = 16t + j (j = i0 digit), 4x float4.
  // 64 lanes x 16 B = 1 KB per wave-instruction, fully coalesced.
  const float4* __restrict__ x4 = reinterpret_cast<const float4*>(x + base + 16 * t);
#pragma unroll
  for (int j = 0; j < 4; ++j) {
    const float4 f = x4[j];
    v[4 * j + 0] = f.x;
    v[4 * j + 1] = f.y;
    v[4 * j + 2] = f.z;
    v[4 * j + 3] = f.w;
  }
  wht16(v);  // transform i0

  // LDS layout: addr(i2,i1,i0) = (i2*16 + i1)*STR + i0.  Thread t = (i2*16+i1).
  // Write addr = t*STR + j: 17 odd -> banks span all 32, 2-way max (free).
#pragma unroll
  for (int j = 0; j < 16; ++j) lds[t * STR + j] = v[j];
  __syncthreads();

  // ---- R2: thread t owns (i2 = t>>4, i0 = t&15), vary i1 = r.
  // addr%32 = 16*((t>>4)&1) + (t&15) + const -> 2-way max (free).
  {
    const int i2 = t >> 4, i0 = t & 15;
#pragma unroll
    for (int r = 0; r < 16; ++r) v[r] = lds[(i2 * 16 + r) * STR + i0];
    wht16(v);  // transform i1
    // write back to the same addresses this thread read -> no barrier first
#pragma unroll
    for (int r = 0; r < 16; ++r) lds[(i2 * 16 + r) * STR + i0] = v[r];
  }
  __syncthreads();

  // ---- R3: thread t owns (i1 = t>>4, i0 = t&15), vary i2 = r.
  // Worst bank multiplicity 3-way (minor).
  {
    const int i1 = t >> 4, i0 = t & 15;
#pragma unroll
    for (int r = 0; r < 16; ++r) v[r] = lds[(r * 16 + i1) * STR + i0];
  }
  wht16(v);  // transform i2

  // ---- Epilogue: thread t holds e(r) = r*256 + t. Stores: 64 lanes cover
  // 256 contiguous bytes per instruction. Nontemporal: out is never re-read.
  const float norm = 0.015625f;  // 1/sqrt(4096)
#pragma unroll
  for (int r = 0; r < 16; ++r) {
    const int c = r * 256 + t;
    const float o = fmaf(scale[c], v[r] * norm, shift[c]);
    __builtin_nontemporal_store(o, out + base + c);
  }
}

extern "C" void kernel_launch(void* const* d_in, const int* in_sizes, int n_in,
                              void* d_out, int out_size, void* d_ws, size_t ws_size,
                              hipStream_t stream) {
  const float* x = (const float*)d_in[0];
  const float* scale = (const float*)d_in[1];
  const float* shift = (const float*)d_in[2];
  float* out = (float*)d_out;

  const int rows = in_sizes[0] / ROW;  // 4*4096 = 16384
  AdaptiveHadamardTransform_kernel<<<rows, 256, 0, stream>>>(x, scale, shift, out);
}